// Round 1
// baseline (1781.590 us; speedup 1.0000x reference)
//
#include <hip/hip_runtime.h>
#include <hip/hip_bf16.h>

// ComplexSympNet fused kernel — MI355X gfx950.
// B=65536, N=L=128, NL=8. All inputs fp32; matmuls via bf16 MFMA 16x16x32.
// Block: 256 threads (4 waves), BM=32 rows. Wave w owns output cols [32w,32w+32).
// State (q,p + 4 output accumulators) register-resident in MFMA C/D layout:
//   tile (m, cc): row = m*16 + (lane>>4)*4 + j, col = (2*wv+cc)*16 + (lane&15)

typedef __attribute__((ext_vector_type(8))) short  short8;   // 8 x bf16 (4 VGPR)
typedef __attribute__((ext_vector_type(4))) float  f32x4;    // MFMA C/D

#define N_DIM 128
#define L_DIM 128
#define NLAYER 8
#define BM 32
#define B_TOTAL 65536

__device__ __forceinline__ unsigned short f2bf(float f) {
    union { float f; unsigned u; } c; c.f = f;
    unsigned r = c.u + 0x7FFFu + ((c.u >> 16) & 1u);   // round-to-nearest-even
    return (unsigned short)(r >> 16);
}

__device__ __forceinline__ float tanh_fast(float x) {
    float e = __expf(2.0f * x);
    return __fdividef(e - 1.0f, e + 1.0f);
}

__device__ __forceinline__ short8 pack_row8(const float* __restrict__ p) {
    const f32x4* v = (const f32x4*)p;
    f32x4 a = v[0], b = v[1];
    short8 r;
    r[0] = (short)f2bf(a[0]); r[1] = (short)f2bf(a[1]);
    r[2] = (short)f2bf(a[2]); r[3] = (short)f2bf(a[3]);
    r[4] = (short)f2bf(b[0]); r[5] = (short)f2bf(b[1]);
    r[6] = (short)f2bf(b[2]); r[7] = (short)f2bf(b[3]);
    return r;
}

__device__ __forceinline__ short8 neg8(short8 v) {
    short8 r;
    #pragma unroll
    for (int k = 0; k < 8; ++k) r[k] = (short)(((unsigned short)v[k]) ^ 0x8000u);
    return r;
}

__global__ __launch_bounds__(256, 2) void symp_fused(
    const float* __restrict__ p_r0, const float* __restrict__ p_i0,
    const float* __restrict__ q_r0, const float* __restrict__ q_i0,
    const float* __restrict__ Wr,   const float* __restrict__ Wi,
    const float* __restrict__ br,   const float* __restrict__ bi,
    const float* __restrict__ bias, const float* __restrict__ diag,
    const float* __restrict__ av,   float* __restrict__ out)
{
    // [32][128] bf16, XOR-swizzled: byte_in_row = (2*col) ^ ((row&7)<<4)
    __shared__ unsigned char sRe[BM * 256];
    __shared__ unsigned char sIm[BM * 256];

    const int tid  = threadIdx.x;
    const int wv   = tid >> 6;        // wave 0..3
    const int lane = tid & 63;
    const int l15  = lane & 15;
    const int l4   = lane >> 4;       // 0..3
    const long row0 = (long)blockIdx.x * BM;

    // register state, C/D layout
    float qr[2][2][4], qi[2][2][4], pr[2][2][4], pi[2][2][4];
    float qcr[2][2][4], qci[2][2][4], pcr[2][2][4], pci[2][2][4];

    #pragma unroll
    for (int m = 0; m < 2; ++m)
    #pragma unroll
    for (int cc = 0; cc < 2; ++cc)
    #pragma unroll
    for (int j = 0; j < 4; ++j) {
        long r = row0 + m*16 + l4*4 + j;
        int  c = (2*wv + cc)*16 + l15;
        long idx = r * N_DIM + c;
        float vqr = q_r0[idx], vqi = q_i0[idx];
        float vpr = p_r0[idx], vpi = p_i0[idx];
        qr[m][cc][j] = vqr;  qi[m][cc][j] = vqi;
        pr[m][cc][j] = vpr;  pi[m][cc][j] = vpi;
        qcr[m][cc][j] = vqr; qci[m][cc][j] = vqi;
        pcr[m][cc][j] = vpr; pci[m][cc][j] = vpi;
    }

    for (int l = 0; l < NLAYER; ++l) {
        const float a_r = av[l*4+0], a_i = av[l*4+1];
        const float b_r = av[l*4+2], b_i = av[l*4+3];

        __syncthreads();   // previous layer's LDS reads must finish before overwrite

        // ---- Phase A: real/imag mix -> LDS bf16 (swizzled) ----
        #pragma unroll
        for (int m = 0; m < 2; ++m)
        #pragma unroll
        for (int cc = 0; cc < 2; ++cc)
        #pragma unroll
        for (int j = 0; j < 4; ++j) {
            int r = m*16 + l4*4 + j;
            int c = (2*wv + cc)*16 + l15;
            float vq_r = qr[m][cc][j], vq_i = qi[m][cc][j];
            float vp_r = pr[m][cc][j], vp_i = pi[m][cc][j];
            float re = a_r*vq_r - a_i*vq_i + b_r*vp_r - b_i*vp_i;
            float im = a_r*vq_i + a_i*vq_r + b_r*vp_i + b_i*vp_r;
            int off = r*256 + ((2*c) ^ ((r & 7) << 4));
            *(unsigned short*)(sRe + off) = f2bf(re);
            *(unsigned short*)(sIm + off) = f2bf(im);
        }

        __syncthreads();

        // ---- Phase B: [BM,N] @ W^T -> [BM,L]  (contraction over n) ----
        f32x4 aRe[2][2], aIm[2][2];
        #pragma unroll
        for (int m = 0; m < 2; ++m)
        #pragma unroll
        for (int cc = 0; cc < 2; ++cc) {
            aRe[m][cc] = (f32x4){0.f,0.f,0.f,0.f};
            aIm[m][cc] = (f32x4){0.f,0.f,0.f,0.f};
        }

        #pragma unroll
        for (int t = 0; t < 4; ++t) {
            int kb = t*32 + l4*8;
            short8 fRe[2], fIm[2], fImN[2];
            #pragma unroll
            for (int m = 0; m < 2; ++m) {
                int r = m*16 + l15;
                int off = r*256 + ((2*kb) ^ ((r & 7) << 4));
                fRe[m]  = *(const short8*)(sRe + off);
                fIm[m]  = *(const short8*)(sIm + off);
                fImN[m] = neg8(fIm[m]);
            }
            // B frag: B[k=n, col=i] = W[i, n] -> 8 contiguous floats of row i
            short8 fWr[2], fWi[2];
            #pragma unroll
            for (int cc = 0; cc < 2; ++cc) {
                int i = (2*wv + cc)*16 + l15;
                fWr[cc] = pack_row8(Wr + ((long)l*L_DIM + i)*N_DIM + kb);
                fWi[cc] = pack_row8(Wi + ((long)l*L_DIM + i)*N_DIM + kb);
            }
            #pragma unroll
            for (int m = 0; m < 2; ++m)
            #pragma unroll
            for (int cc = 0; cc < 2; ++cc) {
                aRe[m][cc] = __builtin_amdgcn_mfma_f32_16x16x32_bf16(fRe[m],  fWr[cc], aRe[m][cc], 0, 0, 0);
                aRe[m][cc] = __builtin_amdgcn_mfma_f32_16x16x32_bf16(fImN[m], fWi[cc], aRe[m][cc], 0, 0, 0);
                aIm[m][cc] = __builtin_amdgcn_mfma_f32_16x16x32_bf16(fIm[m],  fWr[cc], aIm[m][cc], 0, 0, 0);
                aIm[m][cc] = __builtin_amdgcn_mfma_f32_16x16x32_bf16(fRe[m],  fWi[cc], aIm[m][cc], 0, 0, 0);
            }
        }

        __syncthreads();   // done reading sRe/sIm

        // ---- Phase C: biases + tanh + diag-fold -> LDS (overwrite) ----
        #pragma unroll
        for (int m = 0; m < 2; ++m)
        #pragma unroll
        for (int cc = 0; cc < 2; ++cc) {
            int i = (2*wv + cc)*16 + l15;        // L index
            float brv = br[l*L_DIM + i];
            float biv = bi[l*L_DIM + i];
            float dv  = diag[l*L_DIM + i];
            #pragma unroll
            for (int j = 0; j < 4; ++j) {
                int r = m*16 + l4*4 + j;
                float xr = aRe[m][cc][j] + brv - biv;   // lr_r - li_i
                float xi = aIm[m][cc][j] + brv + biv;   // lr_i + li_r
                float r_ = tanh_fast(xr) * dv;          // diag folded into activation
                float i_ = tanh_fast(xi) * dv;
                int off = r*256 + ((2*i) ^ ((r & 7) << 4));
                *(unsigned short*)(sRe + off) = f2bf(r_);
                *(unsigned short*)(sIm + off) = f2bf(i_);
            }
        }

        __syncthreads();

        // ---- Phase D: [BM,L] @ W -> [BM,N]  (contraction over l-row) ----
        f32x4 cRe[2][2], cIm[2][2];
        #pragma unroll
        for (int m = 0; m < 2; ++m)
        #pragma unroll
        for (int cc = 0; cc < 2; ++cc) {
            cRe[m][cc] = (f32x4){0.f,0.f,0.f,0.f};
            cIm[m][cc] = (f32x4){0.f,0.f,0.f,0.f};
        }

        #pragma unroll
        for (int t = 0; t < 4; ++t) {
            int kb = t*32 + l4*8;
            short8 fRe[2], fIm[2], fImN[2];
            #pragma unroll
            for (int m = 0; m < 2; ++m) {
                int r = m*16 + l15;
                int off = r*256 + ((2*kb) ^ ((r & 7) << 4));
                fRe[m]  = *(const short8*)(sRe + off);
                fIm[m]  = *(const short8*)(sIm + off);
                fImN[m] = neg8(fIm[m]);
            }
            // B frag: B[k=l_row, col=n] = W[l_row, n] -> strided column reads
            short8 fWr[2], fWi[2];
            #pragma unroll
            for (int cc = 0; cc < 2; ++cc) {
                int n = (2*wv + cc)*16 + l15;
                short8 wr8, wi8;
                #pragma unroll
                for (int jj = 0; jj < 8; ++jj) {
                    long ridx = ((long)l*L_DIM + kb + jj)*N_DIM + n;
                    wr8[jj] = (short)f2bf(Wr[ridx]);
                    wi8[jj] = (short)f2bf(Wi[ridx]);
                }
                fWr[cc] = wr8; fWi[cc] = wi8;
            }
            #pragma unroll
            for (int m = 0; m < 2; ++m)
            #pragma unroll
            for (int cc = 0; cc < 2; ++cc) {
                cRe[m][cc] = __builtin_amdgcn_mfma_f32_16x16x32_bf16(fRe[m],  fWr[cc], cRe[m][cc], 0, 0, 0);
                cRe[m][cc] = __builtin_amdgcn_mfma_f32_16x16x32_bf16(fImN[m], fWi[cc], cRe[m][cc], 0, 0, 0);
                cIm[m][cc] = __builtin_amdgcn_mfma_f32_16x16x32_bf16(fIm[m],  fWr[cc], cIm[m][cc], 0, 0, 0);
                cIm[m][cc] = __builtin_amdgcn_mfma_f32_16x16x32_bf16(fRe[m],  fWi[cc], cIm[m][cc], 0, 0, 0);
            }
        }

        // ---- state update (registers only) ----
        #pragma unroll
        for (int m = 0; m < 2; ++m)
        #pragma unroll
        for (int cc = 0; cc < 2; ++cc) {
            int n = (2*wv + cc)*16 + l15;
            float bsv = bias[l*N_DIM + n];
            #pragma unroll
            for (int j = 0; j < 4; ++j) {
                float x = cRe[m][cc][j];            // real2
                float y = cIm[m][cc][j] + bsv;      // imag2
                qr[m][cc][j] += b_r*x - b_i*y;
                qi[m][cc][j] += b_r*y + b_i*x;
                pr[m][cc][j] -= a_r*x - a_i*y;
                pi[m][cc][j] -= a_r*y + a_i*x;
                qcr[m][cc][j] += qr[m][cc][j];
                qci[m][cc][j] += qi[m][cc][j];
                pcr[m][cc][j] += pr[m][cc][j];
                pci[m][cc][j] += pi[m][cc][j];
            }
        }
    }

    // ---- write outputs: stack([pc_r, pc_i, qc_r, qc_i]) ----
    const long BN = (long)B_TOTAL * N_DIM;
    #pragma unroll
    for (int m = 0; m < 2; ++m)
    #pragma unroll
    for (int cc = 0; cc < 2; ++cc)
    #pragma unroll
    for (int j = 0; j < 4; ++j) {
        long r = row0 + m*16 + l4*4 + j;
        int  c = (2*wv + cc)*16 + l15;
        long idx = r * N_DIM + c;
        out[idx]          = pcr[m][cc][j];
        out[BN + idx]     = pci[m][cc][j];
        out[2*BN + idx]   = qcr[m][cc][j];
        out[3*BN + idx]   = qci[m][cc][j];
    }
}

extern "C" void kernel_launch(void* const* d_in, const int* in_sizes, int n_in,
                              void* d_out, int out_size, void* d_ws, size_t ws_size,
                              hipStream_t stream) {
    const float* p_r  = (const float*)d_in[0];
    const float* p_i  = (const float*)d_in[1];
    const float* q_r  = (const float*)d_in[2];
    const float* q_i  = (const float*)d_in[3];
    const float* Wr   = (const float*)d_in[4];
    const float* Wi   = (const float*)d_in[5];
    const float* br   = (const float*)d_in[6];
    const float* bi   = (const float*)d_in[7];
    const float* bias = (const float*)d_in[8];
    const float* diag = (const float*)d_in[9];
    const float* av   = (const float*)d_in[10];
    float* out = (float*)d_out;

    dim3 grid(B_TOTAL / BM);   // 2048
    dim3 block(256);
    symp_fused<<<grid, block, 0, stream>>>(p_r, p_i, q_r, q_i, Wr, Wi,
                                           br, bi, bias, diag, av, out);
}

// Round 2
// 643.527 us; speedup vs baseline: 2.7685x; 2.7685x over previous
//
#include <hip/hip_runtime.h>
#include <hip/hip_bf16.h>

// ComplexSympNet fused kernel v2 — MI355X gfx950.
// B=65536, N=L=128, NL=8. fp32 in/out; matmuls via bf16 MFMA 16x16x32.
//
// Round-2 changes vs round-1 (FETCH 1.2GB, WRITE 446MB, MfmaUtil 3%):
//  * prep kernel packs weights to bf16 in d_ws, BOTH row-major (phase B)
//    and transposed (phase D) -> every B-fragment = one global_load_dwordx4,
//    no per-fragment f2bf, no column-strided scalar loads.
//  * input loads / output stores go through an LDS transpose so global
//    traffic is thread-contiguous float4 (full-line coalescing, kills the
//    partial-line write RMW amplification).

typedef __attribute__((ext_vector_type(8))) short  short8;   // 8 x bf16
typedef __attribute__((ext_vector_type(4))) float  f32x4;

#define N_DIM   128
#define NLAYER  8
#define BM      32
#define B_TOTAL 65536
#define W_ELEMS (NLAYER * N_DIM * N_DIM)   // 131072 per matrix

__device__ __forceinline__ unsigned short f2bf(float f) {
    union { float f; unsigned u; } c; c.f = f;
    unsigned r = c.u + 0x7FFFu + ((c.u >> 16) & 1u);   // round-to-nearest-even
    return (unsigned short)(r >> 16);
}

__device__ __forceinline__ float tanh_fast(float x) {
    float e = __expf(2.0f * x);
    return __fdividef(e - 1.0f, e + 1.0f);
}

__device__ __forceinline__ short8 neg8(short8 v) {
    short8 r;
    #pragma unroll
    for (int k = 0; k < 8; ++k) r[k] = (short)(((unsigned short)v[k]) ^ 0x8000u);
    return r;
}

// ---- prep: fp32 weights -> bf16, row-major + transposed copies in ws ----
__global__ void prep_weights(const float* __restrict__ Wr,
                             const float* __restrict__ Wi,
                             unsigned short* __restrict__ ws) {
    int idx = blockIdx.x * 256 + threadIdx.x;          // 0..131071
    unsigned short* wrB = ws;
    unsigned short* wiB = ws + W_ELEMS;
    unsigned short* wrT = ws + 2 * W_ELEMS;
    unsigned short* wiT = ws + 3 * W_ELEMS;
    float vr = Wr[idx], vi = Wi[idx];
    unsigned short hr = f2bf(vr), hi = f2bf(vi);
    wrB[idx] = hr; wiB[idx] = hi;
    int l = idx >> 14, k = (idx >> 7) & 127, n = idx & 127;
    int tidx = (l << 14) | (n << 7) | k;               // T[l][n][k] = W[l][k][n]
    wrT[tidx] = hr; wiT[tidx] = hi;
}

__global__ __launch_bounds__(256, 2) void symp_fused(
    const float* __restrict__ p_r0, const float* __restrict__ p_i0,
    const float* __restrict__ q_r0, const float* __restrict__ q_i0,
    const unsigned short* __restrict__ wrB, const unsigned short* __restrict__ wiB,
    const unsigned short* __restrict__ wrT, const unsigned short* __restrict__ wiT,
    const float* __restrict__ br,   const float* __restrict__ bi,
    const float* __restrict__ bias, const float* __restrict__ diag,
    const float* __restrict__ av,   float* __restrict__ out)
{
    // 16 KB LDS, three views:
    //  - activations: sRe/sIm [32][128] bf16, XOR-swizzled (byte ^= (row&7)<<4)
    //  - staging:     sStage  [32][128] fp32 (I/O transpose)
    __shared__ __align__(16) unsigned char smem[16384];
    unsigned char* sRe = smem;
    unsigned char* sIm = smem + 8192;
    float* sStage = (float*)smem;

    const int tid  = threadIdx.x;
    const int wv   = tid >> 6;
    const int lane = tid & 63;
    const int l15  = lane & 15;
    const int l4   = lane >> 4;
    const long row0 = (long)blockIdx.x * BM;

    float qr[2][2][4], qi[2][2][4], pr[2][2][4], pi[2][2][4];
    float qcr[2][2][4], qci[2][2][4], pcr[2][2][4], pci[2][2][4];

    // ---- prologue: coalesced float4 loads -> LDS -> C/D-layout registers ----
#define STAGE_IN(SRC, DSTREG, DSTACC)                                          \
    __syncthreads();                                                           \
    {   const f32x4* g = (const f32x4*)(SRC + row0 * N_DIM);                   \
        _Pragma("unroll")                                                      \
        for (int p4 = 0; p4 < 4; ++p4)                                         \
            ((f32x4*)sStage)[p4 * 256 + tid] = g[p4 * 256 + tid];              \
    }                                                                          \
    __syncthreads();                                                           \
    _Pragma("unroll") for (int m = 0; m < 2; ++m)                              \
    _Pragma("unroll") for (int cc = 0; cc < 2; ++cc)                           \
    _Pragma("unroll") for (int j = 0; j < 4; ++j) {                            \
        float v = sStage[(m*16 + l4*4 + j) * N_DIM + (2*wv + cc)*16 + l15];    \
        DSTREG[m][cc][j] = v; DSTACC[m][cc][j] = v;                            \
    }

    STAGE_IN(q_r0, qr, qcr)
    STAGE_IN(q_i0, qi, qci)
    STAGE_IN(p_r0, pr, pcr)
    STAGE_IN(p_i0, pi, pci)
#undef STAGE_IN

    for (int l = 0; l < NLAYER; ++l) {
        const float a_r = av[l*4+0], a_i = av[l*4+1];
        const float b_r = av[l*4+2], b_i = av[l*4+3];

        __syncthreads();   // previous phase's LDS reads done before overwrite

        // ---- Phase A: complex mix -> LDS bf16 (swizzled) ----
        #pragma unroll
        for (int m = 0; m < 2; ++m)
        #pragma unroll
        for (int cc = 0; cc < 2; ++cc)
        #pragma unroll
        for (int j = 0; j < 4; ++j) {
            int r = m*16 + l4*4 + j;
            int c = (2*wv + cc)*16 + l15;
            float vq_r = qr[m][cc][j], vq_i = qi[m][cc][j];
            float vp_r = pr[m][cc][j], vp_i = pi[m][cc][j];
            float re = a_r*vq_r - a_i*vq_i + b_r*vp_r - b_i*vp_i;
            float im = a_r*vq_i + a_i*vq_r + b_r*vp_i + b_i*vp_r;
            int off = r*256 + ((2*c) ^ ((r & 7) << 4));
            *(unsigned short*)(sRe + off) = f2bf(re);
            *(unsigned short*)(sIm + off) = f2bf(im);
        }

        __syncthreads();

        // ---- Phase B: [BM,N] @ W^T -> [BM,L] ----
        f32x4 aRe[2][2], aIm[2][2];
        #pragma unroll
        for (int m = 0; m < 2; ++m)
        #pragma unroll
        for (int cc = 0; cc < 2; ++cc) {
            aRe[m][cc] = (f32x4){0.f,0.f,0.f,0.f};
            aIm[m][cc] = (f32x4){0.f,0.f,0.f,0.f};
        }

        #pragma unroll
        for (int t = 0; t < 4; ++t) {
            int kb = t*32 + l4*8;
            short8 fRe[2], fIm[2], fImN[2];
            #pragma unroll
            for (int m = 0; m < 2; ++m) {
                int r = m*16 + l15;
                int off = r*256 + ((2*kb) ^ ((r & 7) << 4));
                fRe[m]  = *(const short8*)(sRe + off);
                fIm[m]  = *(const short8*)(sIm + off);
                fImN[m] = neg8(fIm[m]);
            }
            // B-frag (k=n, col=i): row i of row-major bf16 W -> one dwordx4
            short8 fWr[2], fWi[2];
            #pragma unroll
            for (int cc = 0; cc < 2; ++cc) {
                int i = (2*wv + cc)*16 + l15;
                long o = (((long)(l << 7) + i) << 7) + kb;
                fWr[cc] = *(const short8*)(wrB + o);
                fWi[cc] = *(const short8*)(wiB + o);
            }
            #pragma unroll
            for (int m = 0; m < 2; ++m)
            #pragma unroll
            for (int cc = 0; cc < 2; ++cc) {
                aRe[m][cc] = __builtin_amdgcn_mfma_f32_16x16x32_bf16(fRe[m],  fWr[cc], aRe[m][cc], 0, 0, 0);
                aRe[m][cc] = __builtin_amdgcn_mfma_f32_16x16x32_bf16(fImN[m], fWi[cc], aRe[m][cc], 0, 0, 0);
                aIm[m][cc] = __builtin_amdgcn_mfma_f32_16x16x32_bf16(fIm[m],  fWr[cc], aIm[m][cc], 0, 0, 0);
                aIm[m][cc] = __builtin_amdgcn_mfma_f32_16x16x32_bf16(fRe[m],  fWi[cc], aIm[m][cc], 0, 0, 0);
            }
        }

        __syncthreads();

        // ---- Phase C: biases + tanh + diag-fold -> LDS (overwrite) ----
        #pragma unroll
        for (int m = 0; m < 2; ++m)
        #pragma unroll
        for (int cc = 0; cc < 2; ++cc) {
            int i = (2*wv + cc)*16 + l15;
            float brv = br[l*N_DIM + i];
            float biv = bi[l*N_DIM + i];
            float dv  = diag[l*N_DIM + i];
            #pragma unroll
            for (int j = 0; j < 4; ++j) {
                int r = m*16 + l4*4 + j;
                float xr = aRe[m][cc][j] + brv - biv;   // lr_r - li_i
                float xi = aIm[m][cc][j] + brv + biv;   // lr_i + li_r
                float r_ = tanh_fast(xr) * dv;
                float i_ = tanh_fast(xi) * dv;
                int off = r*256 + ((2*i) ^ ((r & 7) << 4));
                *(unsigned short*)(sRe + off) = f2bf(r_);
                *(unsigned short*)(sIm + off) = f2bf(i_);
            }
        }

        __syncthreads();

        // ---- Phase D: [BM,L] @ W -> [BM,N] ----
        f32x4 cRe[2][2], cIm[2][2];
        #pragma unroll
        for (int m = 0; m < 2; ++m)
        #pragma unroll
        for (int cc = 0; cc < 2; ++cc) {
            cRe[m][cc] = (f32x4){0.f,0.f,0.f,0.f};
            cIm[m][cc] = (f32x4){0.f,0.f,0.f,0.f};
        }

        #pragma unroll
        for (int t = 0; t < 4; ++t) {
            int kb = t*32 + l4*8;
            short8 fRe[2], fIm[2], fImN[2];
            #pragma unroll
            for (int m = 0; m < 2; ++m) {
                int r = m*16 + l15;
                int off = r*256 + ((2*kb) ^ ((r & 7) << 4));
                fRe[m]  = *(const short8*)(sRe + off);
                fIm[m]  = *(const short8*)(sIm + off);
                fImN[m] = neg8(fIm[m]);
            }
            // B-frag (k=l_row, col=n): row n of TRANSPOSED bf16 W -> one dwordx4
            short8 fWr[2], fWi[2];
            #pragma unroll
            for (int cc = 0; cc < 2; ++cc) {
                int n = (2*wv + cc)*16 + l15;
                long o = (((long)(l << 7) + n) << 7) + kb;
                fWr[cc] = *(const short8*)(wrT + o);
                fWi[cc] = *(const short8*)(wiT + o);
            }
            #pragma unroll
            for (int m = 0; m < 2; ++m)
            #pragma unroll
            for (int cc = 0; cc < 2; ++cc) {
                cRe[m][cc] = __builtin_amdgcn_mfma_f32_16x16x32_bf16(fRe[m],  fWr[cc], cRe[m][cc], 0, 0, 0);
                cRe[m][cc] = __builtin_amdgcn_mfma_f32_16x16x32_bf16(fImN[m], fWi[cc], cRe[m][cc], 0, 0, 0);
                cIm[m][cc] = __builtin_amdgcn_mfma_f32_16x16x32_bf16(fIm[m],  fWr[cc], cIm[m][cc], 0, 0, 0);
                cIm[m][cc] = __builtin_amdgcn_mfma_f32_16x16x32_bf16(fRe[m],  fWi[cc], cIm[m][cc], 0, 0, 0);
            }
        }

        // ---- state update (registers only) ----
        #pragma unroll
        for (int m = 0; m < 2; ++m)
        #pragma unroll
        for (int cc = 0; cc < 2; ++cc) {
            int n = (2*wv + cc)*16 + l15;
            float bsv = bias[l*N_DIM + n];
            #pragma unroll
            for (int j = 0; j < 4; ++j) {
                float x = cRe[m][cc][j];            // real2
                float y = cIm[m][cc][j] + bsv;      // imag2
                qr[m][cc][j] += b_r*x - b_i*y;
                qi[m][cc][j] += b_r*y + b_i*x;
                pr[m][cc][j] -= a_r*x - a_i*y;
                pi[m][cc][j] -= a_r*y + a_i*x;
                qcr[m][cc][j] += qr[m][cc][j];
                qci[m][cc][j] += qi[m][cc][j];
                pcr[m][cc][j] += pr[m][cc][j];
                pci[m][cc][j] += pi[m][cc][j];
            }
        }
    }

    // ---- epilogue: registers -> LDS -> coalesced float4 stores ----
    const long BN = (long)B_TOTAL * N_DIM;
#define STAGE_OUT(SRCACC, ARR)                                                 \
    __syncthreads();                                                           \
    _Pragma("unroll") for (int m = 0; m < 2; ++m)                              \
    _Pragma("unroll") for (int cc = 0; cc < 2; ++cc)                           \
    _Pragma("unroll") for (int j = 0; j < 4; ++j)                              \
        sStage[(m*16 + l4*4 + j) * N_DIM + (2*wv + cc)*16 + l15] =             \
            SRCACC[m][cc][j];                                                  \
    __syncthreads();                                                           \
    {   f32x4* g = (f32x4*)(out + (long)(ARR) * BN + row0 * N_DIM);            \
        _Pragma("unroll")                                                      \
        for (int p4 = 0; p4 < 4; ++p4)                                         \
            g[p4 * 256 + tid] = ((const f32x4*)sStage)[p4 * 256 + tid];        \
    }

    STAGE_OUT(pcr, 0)
    STAGE_OUT(pci, 1)
    STAGE_OUT(qcr, 2)
    STAGE_OUT(qci, 3)
#undef STAGE_OUT
}

extern "C" void kernel_launch(void* const* d_in, const int* in_sizes, int n_in,
                              void* d_out, int out_size, void* d_ws, size_t ws_size,
                              hipStream_t stream) {
    const float* p_r  = (const float*)d_in[0];
    const float* p_i  = (const float*)d_in[1];
    const float* q_r  = (const float*)d_in[2];
    const float* q_i  = (const float*)d_in[3];
    const float* Wr   = (const float*)d_in[4];
    const float* Wi   = (const float*)d_in[5];
    const float* br   = (const float*)d_in[6];
    const float* bi   = (const float*)d_in[7];
    const float* bias = (const float*)d_in[8];
    const float* diag = (const float*)d_in[9];
    const float* av   = (const float*)d_in[10];
    float* out = (float*)d_out;

    unsigned short* ws = (unsigned short*)d_ws;   // 4 * 256 KB = 1 MB used
    prep_weights<<<W_ELEMS / 256, 256, 0, stream>>>(Wr, Wi, ws);

    const unsigned short* wrB = ws;
    const unsigned short* wiB = ws + W_ELEMS;
    const unsigned short* wrT = ws + 2 * W_ELEMS;
    const unsigned short* wiT = ws + 3 * W_ELEMS;

    dim3 grid(B_TOTAL / BM);   // 2048
    dim3 block(256);
    symp_fused<<<grid, block, 0, stream>>>(p_r, p_i, q_r, q_i,
                                           wrB, wiB, wrT, wiT,
                                           br, bi, bias, diag, av, out);
}